// Round 2
// baseline (439.164 us; speedup 1.0000x reference)
//
#include <hip/hip_runtime.h>

#define BB 4
#define NN 32768
#define KKN 16          // neighbors per node
#define IN_DIM 32
#define HID 64
#define OUT_DIM 32
#define KH 64
#define WS 88           // LDS row stride in f16 elems (176 B, 16B-aligned)
#define TOT (BB * NN)   // 131072 = 2^17
#define NWAVES 4096     // grid 1024 blocks x 4 waves (exactly 4 blocks/CU co-resident)

typedef _Float16 f16;
typedef f16 f16x2 __attribute__((ext_vector_type(2)));
typedef f16 f16x4 __attribute__((ext_vector_type(4)));
typedef f16 f16x8 __attribute__((ext_vector_type(8)));
typedef float f32x4 __attribute__((ext_vector_type(4)));
typedef __fp16 hf16x2 __attribute__((ext_vector_type(2)));   // builtin's native type

#define H2(c) ((f16x2){(f16)(c), (f16)(c)})

// packed f32->f16x2 convert (v_cvt_pkrtz_f16_f32), bit-cast to _Float16 vec
__device__ __forceinline__ f16x2 cvt2(float a, float b) {
    hf16x2 r = __builtin_amdgcn_cvt_pkrtz(a, b);
    return __builtin_bit_cast(f16x2, r);
}

// Packed-fp16 polynomial gelu, 2 values per call, no transcendentals, no LDS.
// gelu(x) = x*(0.5 + f), f = s*g(s^2), s = clamp(x,±3.5).
// g evaluated in t = (s/4)^2 so coefficients are O(1) (no fp16 subnormals).
// Chebyshev fit on u in [0,12.25], constrained g(12.25)=0.5/3.5 so the
// clamped tail saturates to out ~= x (err < 3e-3 for |x| up to ~6).
__device__ __forceinline__ f16x2 gelu2(float a, float b) {
    f16x2 x  = cvt2(a, b);
    f16x2 s  = __builtin_elementwise_min(
                   __builtin_elementwise_max(x, H2(-3.5f)), H2(3.5f));
    f16x2 s4 = s * H2(0.25f);
    f16x2 t  = s4 * s4;                       // = s^2/16, in [0, 0.765625]
    f16x2 g  = H2(-1.0110344f);
    g = g * t + H2( 2.85016064f);
    g = g * t + H2(-3.40439040f);
    g = g * t + H2( 2.32402432f);
    g = g * t + H2(-1.04974080f);
    g = g * t + H2( 0.39879504f);
    f16x2 f  = s * g;                         // ~= Phi(s) - 0.5
    f16x2 hx = x * H2(0.5f);
    return x * f + hx;                        // x * Phi(clamp(x))
}

// DPP add: v += lane-permuted v (within 16-lane row). CTRL immediate:
// 0xB1=quad_perm xor1, 0x4E=quad_perm xor2, 0x124=row_ror:4, 0x128=row_ror:8.
template <int CTRL>
__device__ __forceinline__ float dppadd(float v) {
    union { float f; int i; } u, r;
    u.f = v;
    r.i = __builtin_amdgcn_update_dpp(0, u.i, CTRL, 0xf, 0xf, true);
    return v + r.f;
}
__device__ __forceinline__ float rowsum16(float v) {
    v = dppadd<0xB1>(v);    // quad xor 1
    v = dppadd<0x4E>(v);    // quad xor 2
    v = dppadd<0x124>(v);   // row rotate 4
    v = dppadd<0x128>(v);   // row rotate 8
    return v;
}

// ---------------- Kernel A: point MLP via MFMA (persistent) ----------------
__global__ __launch_bounds__(256) void point_mlp_kernel(
    const float* __restrict__ inp, const float* __restrict__ Wp1,
    const float* __restrict__ bp1, const float* __restrict__ Wp2,
    const float* __restrict__ bp2, f16* __restrict__ xhf)
{
    __shared__ __align__(16) f16 hb[4][16 * WS];
    const int tid = threadIdx.x, w = tid >> 6, lane = tid & 63;
    const int q = lane >> 4, nl = lane & 15;

    f16x8 w1f[4];
    #pragma unroll
    for (int nb = 0; nb < 4; nb++)
        #pragma unroll
        for (int j = 0; j < 8; j++)
            w1f[nb][j] = (f16)Wp1[(q * 8 + j) * HID + nb * 16 + nl];
    f16x8 w2f[2][2];        // rows pre-permuted by p_inv(k) = (k&3)*16 + k/4
    #pragma unroll
    for (int nb = 0; nb < 2; nb++)
        #pragma unroll
        for (int c = 0; c < 2; c++)
            #pragma unroll
            for (int j = 0; j < 8; j++) {
                int k = c * 32 + q * 8 + j, kp = ((k & 3) << 4) | (k >> 2);
                w2f[nb][c][j] = (f16)Wp2[kp * OUT_DIM + nb * 16 + nl];
            }
    float b1v[4], b2v[2];
    #pragma unroll
    for (int nb = 0; nb < 4; nb++) b1v[nb] = bp1[nb * 16 + nl];
    b2v[0] = bp2[nl]; b2v[1] = bp2[16 + nl];

    const int gw = blockIdx.x * 4 + w;
    const int nw = gridDim.x * 4;

    for (int t = gw; t < TOT / 16; t += nw) {
        const int R = t * 16;
        const float* ap = inp + (size_t)(R + nl) * IN_DIM + q * 8;
        float4 av0 = *(const float4*)ap, av1 = *(const float4*)(ap + 4);
        f16x2 p01 = cvt2(av0.x, av0.y);
        f16x2 p23 = cvt2(av0.z, av0.w);
        f16x2 p45 = cvt2(av1.x, av1.y);
        f16x2 p67 = cvt2(av1.z, av1.w);
        f16x8 af = (f16x8){p01.x, p01.y, p23.x, p23.y, p45.x, p45.y, p67.x, p67.y};

        f32x4 acc[4];
        #pragma unroll
        for (int nb = 0; nb < 4; nb++)
            acc[nb] = (f32x4){b1v[nb], b1v[nb], b1v[nb], b1v[nb]};
        #pragma unroll
        for (int nb = 0; nb < 4; nb++)
            acc[nb] = __builtin_amdgcn_mfma_f32_16x16x32_f16(af, w1f[nb], acc[nb], 0, 0, 0);

        #pragma unroll
        for (int r = 0; r < 4; r++) {
            f16x2 h01 = gelu2(acc[0][r], acc[1][r]);
            f16x2 h23 = gelu2(acc[2][r], acc[3][r]);
            *(f16x4*)&hb[w][(q * 4 + r) * WS + nl * 4] = (f16x4){h01.x, h01.y, h23.x, h23.y};
        }
        f16x8 a0 = *(const f16x8*)&hb[w][nl * WS + q * 8];
        f16x8 a1 = *(const f16x8*)&hb[w][nl * WS + 32 + q * 8];
        f32x4 a2[2];
        #pragma unroll
        for (int nb = 0; nb < 2; nb++) {
            a2[nb] = (f32x4){b2v[nb], b2v[nb], b2v[nb], b2v[nb]};
            a2[nb] = __builtin_amdgcn_mfma_f32_16x16x32_f16(a0, w2f[nb][0], a2[nb], 0, 0, 0);
            a2[nb] = __builtin_amdgcn_mfma_f32_16x16x32_f16(a1, w2f[nb][1], a2[nb], 0, 0, 0);
        }
        #pragma unroll
        for (int r = 0; r < 4; r++)
            #pragma unroll
            for (int nb = 0; nb < 2; nb++)
                xhf[(size_t)(R + q * 4 + r) * OUT_DIM + nb * 16 + nl] = (f16)a2[nb][r];
    }
}

// ---------------- Kernel B: edge MLP, 2 nodes/iter, packed-f16 poly gelu ----------------
__global__ __launch_bounds__(256, 4) void gnn_edge_kernel(
    const f16*   __restrict__ xhf,
    const float* __restrict__ igrid, const float* __restrict__ ogrid,
    const int*   __restrict__ nbi,
    const float* __restrict__ Wk1, const float* __restrict__ bk1,
    const float* __restrict__ Wk2, const float* __restrict__ bk2,
    const float* __restrict__ Wk3, const float* __restrict__ bk3,
    const float* __restrict__ gma, const float* __restrict__ bta,
    float* __restrict__ out)
{
    __shared__ __align__(16) f16 tile[8][16 * WS];   // 2 tiles per wave (22.5 KB)

    const int tid = threadIdx.x, w = tid >> 6, lane = tid & 63;
    const int q = lane >> 4, nl = lane & 15;
    f16* __restrict__ TA = tile[w * 2];
    f16* __restrict__ TB = tile[w * 2 + 1];

    // ---- weight B-frags in registers ----
    f16x8 w1f[4][2], w2f[4][2], w3f[2][2];
    #pragma unroll
    for (int nb = 0; nb < 4; nb++) {
        #pragma unroll
        for (int j = 0; j < 8; j++) {
            w1f[nb][0][j] = (f16)Wk1[(4 + q * 8 + j) * KH + nb * 16 + nl];
            float v1 = 0.0f;
            if (j < 4 && q == 0) v1 = Wk1[j * KH + nb * 16 + nl];
            w1f[nb][1][j] = (f16)v1;
        }
        #pragma unroll
        for (int c = 0; c < 2; c++)
            #pragma unroll
            for (int j = 0; j < 8; j++) {
                int k = c * 32 + q * 8 + j, kp = ((k & 3) << 4) | (k >> 2);
                w2f[nb][c][j] = (f16)Wk2[kp * KH + nb * 16 + nl];
            }
    }
    #pragma unroll
    for (int nb = 0; nb < 2; nb++)
        #pragma unroll
        for (int c = 0; c < 2; c++)
            #pragma unroll
            for (int j = 0; j < 8; j++) {
                int k = c * 32 + q * 8 + j, kp = ((k & 3) << 4) | (k >> 2);
                w3f[nb][c][j] = (f16)Wk3[kp * OUT_DIM + nb * 16 + nl];
            }

    float b1v[4], b2v[4], b3v[2];
    #pragma unroll
    for (int nb = 0; nb < 4; nb++) { b1v[nb] = bk1[nb * 16 + nl]; b2v[nb] = bk2[nb * 16 + nl]; }
    b3v[0] = bk3[nl]; b3v[1] = bk3[16 + nl];
    const float g0 = gma[nl], g1 = gma[16 + nl], be0 = bta[nl], be1 = bta[16 + nl];

    const int gw = blockIdx.x * 4 + w;
    const int e = lane >> 2, part = lane & 3;

    // zero both tiles fully once (cols 36..63 stay zero forever; 0..35 rewritten per task)
    // tiles are wave-private: no barrier needed anywhere.
    {
        const f16x8 zf = {(f16)0.f,(f16)0.f,(f16)0.f,(f16)0.f,(f16)0.f,(f16)0.f,(f16)0.f,(f16)0.f};
        for (int i = lane * 8; i < 16 * WS; i += 64 * 8) { *(f16x8*)&TA[i] = zf; *(f16x8*)&TB[i] = zf; }
    }

    // ---- prologue prefetch (pair 0) ----
    int tA = gw, tB = gw + NWAVES;
    int nA = nbi[(tA & (NN - 1)) * KKN + e];
    int nB = nbi[(tB & (NN - 1)) * KKN + e];
    uint4 fyA = ((const uint4*)(xhf + ((size_t)((tA >> 15) * NN + nA)) * OUT_DIM))[part];
    uint4 fyB = ((const uint4*)(xhf + ((size_t)((tB >> 15) * NN + nB)) * OUT_DIM))[part];
    float2 ipA, opA, ipB, opB;
    if (part == 0) {
        ipA = ((const float2*)igrid)[nA]; opA = ((const float2*)ogrid)[tA & (NN - 1)];
        ipB = ((const float2*)igrid)[nB]; opB = ((const float2*)ogrid)[tB & (NN - 1)];
    }
    f16 xA0 = xhf[(size_t)tA * OUT_DIM + nl],      xA1 = xhf[(size_t)tA * OUT_DIM + 16 + nl];
    f16 xB0 = xhf[(size_t)tB * OUT_DIM + nl],      xB1 = xhf[(size_t)tB * OUT_DIM + 16 + nl];

    #pragma unroll 1
    for (int it = 0; it < TOT / (2 * NWAVES); ++it) {
        // ---- commit prefetched gathers ----
        *(uint4*)&TA[e * WS + part * 8] = fyA;
        *(uint4*)&TB[e * WS + part * 8] = fyB;
        if (part == 0) {
            f16x4 pA = {(f16)ipA.x, (f16)ipA.y, (f16)opA.x, (f16)opA.y};
            f16x4 pB = {(f16)ipB.x, (f16)ipB.y, (f16)opB.x, (f16)opB.y};
            *(f16x4*)&TA[e * WS + 32] = pA;
            *(f16x4*)&TB[e * WS + 32] = pB;
        }
        const float rA0 = (float)xA0, rA1 = (float)xA1, rB0 = (float)xB0, rB1 = (float)xB1;

        // ---- next pair indices (wraparound, always valid) ----
        const int tA2 = (tA + 2 * NWAVES) & (TOT - 1);
        const int tB2 = tA2 + NWAVES;
        const int nA2 = nbi[(tA2 & (NN - 1)) * KKN + e];
        const int nB2 = nbi[(tB2 & (NN - 1)) * KKN + e];

        // ---- layer 1 (A and B interleaved) ----
        f16x8 aA0 = *(const f16x8*)&TA[nl * WS + q * 8];
        f16x8 aA1 = *(const f16x8*)&TA[nl * WS + 32 + q * 8];
        f16x8 aB0 = *(const f16x8*)&TB[nl * WS + q * 8];
        f16x8 aB1 = *(const f16x8*)&TB[nl * WS + 32 + q * 8];
        f32x4 cA[4], cB[4];
        #pragma unroll
        for (int nb = 0; nb < 4; nb++) {
            cA[nb] = (f32x4){b1v[nb], b1v[nb], b1v[nb], b1v[nb]};
            cB[nb] = (f32x4){b1v[nb], b1v[nb], b1v[nb], b1v[nb]};
        }
        #pragma unroll
        for (int nb = 0; nb < 4; nb++) {
            cA[nb] = __builtin_amdgcn_mfma_f32_16x16x32_f16(aA0, w1f[nb][0], cA[nb], 0, 0, 0);
            cB[nb] = __builtin_amdgcn_mfma_f32_16x16x32_f16(aB0, w1f[nb][0], cB[nb], 0, 0, 0);
            cA[nb] = __builtin_amdgcn_mfma_f32_16x16x32_f16(aA1, w1f[nb][1], cA[nb], 0, 0, 0);
            cB[nb] = __builtin_amdgcn_mfma_f32_16x16x32_f16(aB1, w1f[nb][1], cB[nb], 0, 0, 0);
        }
        #pragma unroll
        for (int r = 0; r < 4; r++) {
            f16x2 hA01 = gelu2(cA[0][r], cA[1][r]);
            f16x2 hA23 = gelu2(cA[2][r], cA[3][r]);
            f16x2 hB01 = gelu2(cB[0][r], cB[1][r]);
            f16x2 hB23 = gelu2(cB[2][r], cB[3][r]);
            *(f16x4*)&TA[(q * 4 + r) * WS + nl * 4] = (f16x4){hA01.x, hA01.y, hA23.x, hA23.y};
            *(f16x4*)&TB[(q * 4 + r) * WS + nl * 4] = (f16x4){hB01.x, hB01.y, hB23.x, hB23.y};
        }

        // ---- issue next pair's gathers (overlap layers 2-3) ----
        uint4 fyA2 = ((const uint4*)(xhf + ((size_t)((tA2 >> 15) * NN + nA2)) * OUT_DIM))[part];
        uint4 fyB2 = ((const uint4*)(xhf + ((size_t)((tB2 >> 15) * NN + nB2)) * OUT_DIM))[part];
        float2 ipA2, opA2, ipB2, opB2;
        if (part == 0) {
            ipA2 = ((const float2*)igrid)[nA2]; opA2 = ((const float2*)ogrid)[tA2 & (NN - 1)];
            ipB2 = ((const float2*)igrid)[nB2]; opB2 = ((const float2*)ogrid)[tB2 & (NN - 1)];
        }
        f16 xA0n = xhf[(size_t)tA2 * OUT_DIM + nl],  xA1n = xhf[(size_t)tA2 * OUT_DIM + 16 + nl];
        f16 xB0n = xhf[(size_t)tB2 * OUT_DIM + nl],  xB1n = xhf[(size_t)tB2 * OUT_DIM + 16 + nl];

        // ---- layer 2 ----
        aA0 = *(const f16x8*)&TA[nl * WS + q * 8];
        aA1 = *(const f16x8*)&TA[nl * WS + 32 + q * 8];
        aB0 = *(const f16x8*)&TB[nl * WS + q * 8];
        aB1 = *(const f16x8*)&TB[nl * WS + 32 + q * 8];
        #pragma unroll
        for (int nb = 0; nb < 4; nb++) {
            cA[nb] = (f32x4){b2v[nb], b2v[nb], b2v[nb], b2v[nb]};
            cB[nb] = (f32x4){b2v[nb], b2v[nb], b2v[nb], b2v[nb]};
        }
        #pragma unroll
        for (int nb = 0; nb < 4; nb++) {
            cA[nb] = __builtin_amdgcn_mfma_f32_16x16x32_f16(aA0, w2f[nb][0], cA[nb], 0, 0, 0);
            cB[nb] = __builtin_amdgcn_mfma_f32_16x16x32_f16(aB0, w2f[nb][0], cB[nb], 0, 0, 0);
            cA[nb] = __builtin_amdgcn_mfma_f32_16x16x32_f16(aA1, w2f[nb][1], cA[nb], 0, 0, 0);
            cB[nb] = __builtin_amdgcn_mfma_f32_16x16x32_f16(aB1, w2f[nb][1], cB[nb], 0, 0, 0);
        }
        #pragma unroll
        for (int r = 0; r < 4; r++) {
            f16x2 hA01 = gelu2(cA[0][r], cA[1][r]);
            f16x2 hA23 = gelu2(cA[2][r], cA[3][r]);
            f16x2 hB01 = gelu2(cB[0][r], cB[1][r]);
            f16x2 hB23 = gelu2(cB[2][r], cB[3][r]);
            *(f16x4*)&TA[(q * 4 + r) * WS + nl * 4] = (f16x4){hA01.x, hA01.y, hA23.x, hA23.y};
            *(f16x4*)&TB[(q * 4 + r) * WS + nl * 4] = (f16x4){hB01.x, hB01.y, hB23.x, hB23.y};
        }

        // ---- layer 3 ----
        aA0 = *(const f16x8*)&TA[nl * WS + q * 8];
        aA1 = *(const f16x8*)&TA[nl * WS + 32 + q * 8];
        aB0 = *(const f16x8*)&TB[nl * WS + q * 8];
        aB1 = *(const f16x8*)&TB[nl * WS + 32 + q * 8];
        f32x4 dA[2], dB[2];
        #pragma unroll
        for (int nb = 0; nb < 2; nb++) {
            dA[nb] = (f32x4){0.f, 0.f, 0.f, 0.f};
            dB[nb] = (f32x4){0.f, 0.f, 0.f, 0.f};
            dA[nb] = __builtin_amdgcn_mfma_f32_16x16x32_f16(aA0, w3f[nb][0], dA[nb], 0, 0, 0);
            dB[nb] = __builtin_amdgcn_mfma_f32_16x16x32_f16(aB0, w3f[nb][0], dB[nb], 0, 0, 0);
            dA[nb] = __builtin_amdgcn_mfma_f32_16x16x32_f16(aA1, w3f[nb][1], dA[nb], 0, 0, 0);
            dB[nb] = __builtin_amdgcn_mfma_f32_16x16x32_f16(aB1, w3f[nb][1], dB[nb], 0, 0, 0);
        }

        // ---- epilogues: mean over 16 edges + bias + residual, LN over 32 (DPP row sums) ----
        {
            float s0 = dA[0][0] + dA[0][1] + dA[0][2] + dA[0][3];
            float s1 = dA[1][0] + dA[1][1] + dA[1][2] + dA[1][3];
            float u0 = dB[0][0] + dB[0][1] + dB[0][2] + dB[0][3];
            float u1 = dB[1][0] + dB[1][1] + dB[1][2] + dB[1][3];
            s0 += __shfl_xor(s0, 16, 64); s0 += __shfl_xor(s0, 32, 64);
            s1 += __shfl_xor(s1, 16, 64); s1 += __shfl_xor(s1, 32, 64);
            u0 += __shfl_xor(u0, 16, 64); u0 += __shfl_xor(u0, 32, 64);
            u1 += __shfl_xor(u1, 16, 64); u1 += __shfl_xor(u1, 32, 64);

            float oA0 = s0 * 0.0625f + b3v[0] + rA0;
            float oA1 = s1 * 0.0625f + b3v[1] + rA1;
            float oB0 = u0 * 0.0625f + b3v[0] + rB0;
            float oB1 = u1 * 0.0625f + b3v[1] + rB1;

            float mA = rowsum16(oA0 + oA1) * (1.0f / 32.0f);
            float mB = rowsum16(oB0 + oB1) * (1.0f / 32.0f);
            float dA0 = oA0 - mA, dA1 = oA1 - mA, dB0 = oB0 - mB, dB1 = oB1 - mB;
            float vA = rowsum16(dA0 * dA0 + dA1 * dA1) * (1.0f / 32.0f);
            float vB = rowsum16(dB0 * dB0 + dB1 * dB1) * (1.0f / 32.0f);
            float rsA = rsqrtf(vA + 1e-5f);
            float rsB = rsqrtf(vB + 1e-5f);

            if (q == 0) {
                float* oa = out + (size_t)tA * OUT_DIM;
                float* ob = out + (size_t)tB * OUT_DIM;
                oa[nl]      = fmaf(dA0 * rsA, g0, be0);
                oa[16 + nl] = fmaf(dA1 * rsA, g1, be1);
                ob[nl]      = fmaf(dB0 * rsB, g0, be0);
                ob[16 + nl] = fmaf(dB1 * rsB, g1, be1);
            }
        }

        // ---- rotate prefetch state ----
        tA = tA2; tB = tB2;
        fyA = fyA2; fyB = fyB2;
        ipA = ipA2; opA = opA2; ipB = ipB2; opB = opB2;
        xA0 = xA0n; xA1 = xA1n; xB0 = xB0n; xB1 = xB1n;
    }
}

extern "C" void kernel_launch(void* const* d_in, const int* in_sizes, int n_in,
                              void* d_out, int out_size, void* d_ws, size_t ws_size,
                              hipStream_t stream) {
    const float* inp   = (const float*)d_in[0];
    const float* igrid = (const float*)d_in[1];
    const float* ogrid = (const float*)d_in[2];
    const int*   nbi   = (const int*)d_in[3];
    const float* Wp1   = (const float*)d_in[4];
    const float* bp1   = (const float*)d_in[5];
    const float* Wp2   = (const float*)d_in[6];
    const float* bp2   = (const float*)d_in[7];
    const float* Wk1   = (const float*)d_in[8];
    const float* bk1   = (const float*)d_in[9];
    const float* Wk2   = (const float*)d_in[10];
    const float* bk2   = (const float*)d_in[11];
    const float* Wk3   = (const float*)d_in[12];
    const float* bk3   = (const float*)d_in[13];
    const float* gma   = (const float*)d_in[14];
    const float* bta   = (const float*)d_in[15];
    float* out = (float*)d_out;
    f16* xhf = (f16*)d_ws;   // B*N*32 f16 = 8 MB

    point_mlp_kernel<<<1024, 256, 0, stream>>>(inp, Wp1, bp1, Wp2, bp2, xhf);
    gnn_edge_kernel<<<1024, 256, 0, stream>>>(xhf, igrid, ogrid, nbi,
                                              Wk1, bk1, Wk2, bk2, Wk3, bk3,
                                              gma, bta, out);
}

// Round 3
// 205.978 us; speedup vs baseline: 2.1321x; 2.1321x over previous
//
#include <hip/hip_runtime.h>

#define BB 4
#define NN 32768
#define KKN 16          // neighbors per node
#define IN_DIM 32
#define HID 64
#define OUT_DIM 32
#define KH 64
#define WS 88           // LDS row stride in f16 elems (176 B, 16B-aligned)
#define TOT (BB * NN)   // 131072 = 2^17
#define NWAVES 4096     // grid 1024 blocks x 4 waves (4 blocks/CU co-resident at ~116 VGPR)

typedef _Float16 f16;
typedef f16 f16x2 __attribute__((ext_vector_type(2)));
typedef f16 f16x4 __attribute__((ext_vector_type(4)));
typedef f16 f16x8 __attribute__((ext_vector_type(8)));
typedef float f32x4 __attribute__((ext_vector_type(4)));
typedef __fp16 hf16x2 __attribute__((ext_vector_type(2)));   // builtin's native type

#define H2(c) ((f16x2){(f16)(c), (f16)(c)})

// packed f32->f16x2 convert (v_cvt_pkrtz_f16_f32), bit-cast to _Float16 vec
__device__ __forceinline__ f16x2 cvt2(float a, float b) {
    hf16x2 r = __builtin_amdgcn_cvt_pkrtz(a, b);
    return __builtin_bit_cast(f16x2, r);
}

// Packed-fp16 polynomial gelu, 2 values per call, no transcendentals, no LDS.
// gelu(x) = x*(0.5 + f), f = s*g(s^2), s = clamp(x,±3.5).
__device__ __forceinline__ f16x2 gelu2(float a, float b) {
    f16x2 x  = cvt2(a, b);
    f16x2 s  = __builtin_elementwise_min(
                   __builtin_elementwise_max(x, H2(-3.5f)), H2(3.5f));
    f16x2 s4 = s * H2(0.25f);
    f16x2 t  = s4 * s4;                       // = s^2/16, in [0, 0.765625]
    f16x2 g  = H2(-1.0110344f);
    g = g * t + H2( 2.85016064f);
    g = g * t + H2(-3.40439040f);
    g = g * t + H2( 2.32402432f);
    g = g * t + H2(-1.04974080f);
    g = g * t + H2( 0.39879504f);
    f16x2 f  = s * g;                         // ~= Phi(s) - 0.5
    f16x2 hx = x * H2(0.5f);
    return x * f + hx;                        // x * Phi(clamp(x))
}

// DPP add: v += lane-permuted v (within 16-lane row).
template <int CTRL>
__device__ __forceinline__ float dppadd(float v) {
    union { float f; int i; } u, r;
    u.f = v;
    r.i = __builtin_amdgcn_update_dpp(0, u.i, CTRL, 0xf, 0xf, true);
    return v + r.f;
}
__device__ __forceinline__ float rowsum16(float v) {
    v = dppadd<0xB1>(v);    // quad xor 1
    v = dppadd<0x4E>(v);    // quad xor 2
    v = dppadd<0x124>(v);   // row rotate 4
    v = dppadd<0x128>(v);   // row rotate 8
    return v;
}

// ---------------- Kernel A: point MLP via MFMA (persistent) ----------------
__global__ __launch_bounds__(256) void point_mlp_kernel(
    const float* __restrict__ inp, const float* __restrict__ Wp1,
    const float* __restrict__ bp1, const float* __restrict__ Wp2,
    const float* __restrict__ bp2, f16* __restrict__ xhf)
{
    __shared__ __align__(16) f16 hb[4][16 * WS];
    const int tid = threadIdx.x, w = tid >> 6, lane = tid & 63;
    const int q = lane >> 4, nl = lane & 15;

    f16x8 w1f[4];
    #pragma unroll
    for (int nb = 0; nb < 4; nb++)
        #pragma unroll
        for (int j = 0; j < 8; j++)
            w1f[nb][j] = (f16)Wp1[(q * 8 + j) * HID + nb * 16 + nl];
    f16x8 w2f[2][2];        // rows pre-permuted by p_inv(k) = (k&3)*16 + k/4
    #pragma unroll
    for (int nb = 0; nb < 2; nb++)
        #pragma unroll
        for (int c = 0; c < 2; c++)
            #pragma unroll
            for (int j = 0; j < 8; j++) {
                int k = c * 32 + q * 8 + j, kp = ((k & 3) << 4) | (k >> 2);
                w2f[nb][c][j] = (f16)Wp2[kp * OUT_DIM + nb * 16 + nl];
            }
    float b1v[4], b2v[2];
    #pragma unroll
    for (int nb = 0; nb < 4; nb++) b1v[nb] = bp1[nb * 16 + nl];
    b2v[0] = bp2[nl]; b2v[1] = bp2[16 + nl];

    const int gw = blockIdx.x * 4 + w;
    const int nw = gridDim.x * 4;

    for (int t = gw; t < TOT / 16; t += nw) {
        const int R = t * 16;
        const float* ap = inp + (size_t)(R + nl) * IN_DIM + q * 8;
        float4 av0 = *(const float4*)ap, av1 = *(const float4*)(ap + 4);
        f16x2 p01 = cvt2(av0.x, av0.y);
        f16x2 p23 = cvt2(av0.z, av0.w);
        f16x2 p45 = cvt2(av1.x, av1.y);
        f16x2 p67 = cvt2(av1.z, av1.w);
        f16x8 af = (f16x8){p01.x, p01.y, p23.x, p23.y, p45.x, p45.y, p67.x, p67.y};

        f32x4 acc[4];
        #pragma unroll
        for (int nb = 0; nb < 4; nb++)
            acc[nb] = (f32x4){b1v[nb], b1v[nb], b1v[nb], b1v[nb]};
        #pragma unroll
        for (int nb = 0; nb < 4; nb++)
            acc[nb] = __builtin_amdgcn_mfma_f32_16x16x32_f16(af, w1f[nb], acc[nb], 0, 0, 0);

        #pragma unroll
        for (int r = 0; r < 4; r++) {
            f16x2 h01 = gelu2(acc[0][r], acc[1][r]);
            f16x2 h23 = gelu2(acc[2][r], acc[3][r]);
            *(f16x4*)&hb[w][(q * 4 + r) * WS + nl * 4] = (f16x4){h01.x, h01.y, h23.x, h23.y};
        }
        f16x8 a0 = *(const f16x8*)&hb[w][nl * WS + q * 8];
        f16x8 a1 = *(const f16x8*)&hb[w][nl * WS + 32 + q * 8];
        f32x4 a2[2];
        #pragma unroll
        for (int nb = 0; nb < 2; nb++) {
            a2[nb] = (f32x4){b2v[nb], b2v[nb], b2v[nb], b2v[nb]};
            a2[nb] = __builtin_amdgcn_mfma_f32_16x16x32_f16(a0, w2f[nb][0], a2[nb], 0, 0, 0);
            a2[nb] = __builtin_amdgcn_mfma_f32_16x16x32_f16(a1, w2f[nb][1], a2[nb], 0, 0, 0);
        }
        #pragma unroll
        for (int r = 0; r < 4; r++)
            #pragma unroll
            for (int nb = 0; nb < 2; nb++)
                xhf[(size_t)(R + q * 4 + r) * OUT_DIM + nb * 16 + nl] = (f16)a2[nb][r];
    }
}

// ---------------- Kernel B: edge MLP, 2 nodes/iter, packed-f16 poly gelu ----------------
// NOTE: plain __launch_bounds__(256). Forcing min-waves=4 made the allocator
// squeeze to 64 VGPR and spill the ~80-VGPR weight-fragment set to scratch
// (R2: FETCH 92->950 MB, WRITE 16->328 MB). The kernel needs ~116 VGPR live.
__global__ __launch_bounds__(256) void gnn_edge_kernel(
    const f16*   __restrict__ xhf,
    const float* __restrict__ igrid, const float* __restrict__ ogrid,
    const int*   __restrict__ nbi,
    const float* __restrict__ Wk1, const float* __restrict__ bk1,
    const float* __restrict__ Wk2, const float* __restrict__ bk2,
    const float* __restrict__ Wk3, const float* __restrict__ bk3,
    const float* __restrict__ gma, const float* __restrict__ bta,
    float* __restrict__ out)
{
    __shared__ __align__(16) f16 tile[8][16 * WS];   // 2 tiles per wave (22.5 KB)

    const int tid = threadIdx.x, w = tid >> 6, lane = tid & 63;
    const int q = lane >> 4, nl = lane & 15;
    f16* __restrict__ TA = tile[w * 2];
    f16* __restrict__ TB = tile[w * 2 + 1];

    // ---- weight B-frags in registers ----
    f16x8 w1f[4][2], w2f[4][2], w3f[2][2];
    #pragma unroll
    for (int nb = 0; nb < 4; nb++) {
        #pragma unroll
        for (int j = 0; j < 8; j++) {
            w1f[nb][0][j] = (f16)Wk1[(4 + q * 8 + j) * KH + nb * 16 + nl];
            float v1 = 0.0f;
            if (j < 4 && q == 0) v1 = Wk1[j * KH + nb * 16 + nl];
            w1f[nb][1][j] = (f16)v1;
        }
        #pragma unroll
        for (int c = 0; c < 2; c++)
            #pragma unroll
            for (int j = 0; j < 8; j++) {
                int k = c * 32 + q * 8 + j, kp = ((k & 3) << 4) | (k >> 2);
                w2f[nb][c][j] = (f16)Wk2[kp * KH + nb * 16 + nl];
            }
    }
    #pragma unroll
    for (int nb = 0; nb < 2; nb++)
        #pragma unroll
        for (int c = 0; c < 2; c++)
            #pragma unroll
            for (int j = 0; j < 8; j++) {
                int k = c * 32 + q * 8 + j, kp = ((k & 3) << 4) | (k >> 2);
                w3f[nb][c][j] = (f16)Wk3[kp * OUT_DIM + nb * 16 + nl];
            }

    float b1v[4], b2v[4], b3v[2];
    #pragma unroll
    for (int nb = 0; nb < 4; nb++) { b1v[nb] = bk1[nb * 16 + nl]; b2v[nb] = bk2[nb * 16 + nl]; }
    b3v[0] = bk3[nl]; b3v[1] = bk3[16 + nl];
    const float g0 = gma[nl], g1 = gma[16 + nl], be0 = bta[nl], be1 = bta[16 + nl];

    const int gw = blockIdx.x * 4 + w;
    const int e = lane >> 2, part = lane & 3;

    // zero both tiles fully once (cols 36..63 stay zero forever; 0..35 rewritten per task)
    // tiles are wave-private: no barrier needed anywhere.
    {
        const f16x8 zf = {(f16)0.f,(f16)0.f,(f16)0.f,(f16)0.f,(f16)0.f,(f16)0.f,(f16)0.f,(f16)0.f};
        for (int i = lane * 8; i < 16 * WS; i += 64 * 8) { *(f16x8*)&TA[i] = zf; *(f16x8*)&TB[i] = zf; }
    }

    // ---- prologue prefetch (pair 0) ----
    int tA = gw, tB = gw + NWAVES;
    int nA = nbi[(tA & (NN - 1)) * KKN + e];
    int nB = nbi[(tB & (NN - 1)) * KKN + e];
    uint4 fyA = ((const uint4*)(xhf + ((size_t)((tA >> 15) * NN + nA)) * OUT_DIM))[part];
    uint4 fyB = ((const uint4*)(xhf + ((size_t)((tB >> 15) * NN + nB)) * OUT_DIM))[part];
    float2 ipA, opA, ipB, opB;
    if (part == 0) {
        ipA = ((const float2*)igrid)[nA]; opA = ((const float2*)ogrid)[tA & (NN - 1)];
        ipB = ((const float2*)igrid)[nB]; opB = ((const float2*)ogrid)[tB & (NN - 1)];
    }
    f16 xA0 = xhf[(size_t)tA * OUT_DIM + nl],      xA1 = xhf[(size_t)tA * OUT_DIM + 16 + nl];
    f16 xB0 = xhf[(size_t)tB * OUT_DIM + nl],      xB1 = xhf[(size_t)tB * OUT_DIM + 16 + nl];

    #pragma unroll 1
    for (int it = 0; it < TOT / (2 * NWAVES); ++it) {
        // ---- commit prefetched gathers ----
        *(uint4*)&TA[e * WS + part * 8] = fyA;
        *(uint4*)&TB[e * WS + part * 8] = fyB;
        if (part == 0) {
            f16x4 pA = {(f16)ipA.x, (f16)ipA.y, (f16)opA.x, (f16)opA.y};
            f16x4 pB = {(f16)ipB.x, (f16)ipB.y, (f16)opB.x, (f16)opB.y};
            *(f16x4*)&TA[e * WS + 32] = pA;
            *(f16x4*)&TB[e * WS + 32] = pB;
        }
        const float rA0 = (float)xA0, rA1 = (float)xA1, rB0 = (float)xB0, rB1 = (float)xB1;

        // ---- next pair indices (wraparound, always valid) ----
        const int tA2 = (tA + 2 * NWAVES) & (TOT - 1);
        const int tB2 = tA2 + NWAVES;
        const int nA2 = nbi[(tA2 & (NN - 1)) * KKN + e];
        const int nB2 = nbi[(tB2 & (NN - 1)) * KKN + e];

        // ---- layer 1 (A and B interleaved) ----
        f16x8 aA0 = *(const f16x8*)&TA[nl * WS + q * 8];
        f16x8 aA1 = *(const f16x8*)&TA[nl * WS + 32 + q * 8];
        f16x8 aB0 = *(const f16x8*)&TB[nl * WS + q * 8];
        f16x8 aB1 = *(const f16x8*)&TB[nl * WS + 32 + q * 8];
        f32x4 cA[4], cB[4];
        #pragma unroll
        for (int nb = 0; nb < 4; nb++) {
            cA[nb] = (f32x4){b1v[nb], b1v[nb], b1v[nb], b1v[nb]};
            cB[nb] = (f32x4){b1v[nb], b1v[nb], b1v[nb], b1v[nb]};
        }
        #pragma unroll
        for (int nb = 0; nb < 4; nb++) {
            cA[nb] = __builtin_amdgcn_mfma_f32_16x16x32_f16(aA0, w1f[nb][0], cA[nb], 0, 0, 0);
            cB[nb] = __builtin_amdgcn_mfma_f32_16x16x32_f16(aB0, w1f[nb][0], cB[nb], 0, 0, 0);
            cA[nb] = __builtin_amdgcn_mfma_f32_16x16x32_f16(aA1, w1f[nb][1], cA[nb], 0, 0, 0);
            cB[nb] = __builtin_amdgcn_mfma_f32_16x16x32_f16(aB1, w1f[nb][1], cB[nb], 0, 0, 0);
        }
        #pragma unroll
        for (int r = 0; r < 4; r++) {
            f16x2 hA01 = gelu2(cA[0][r], cA[1][r]);
            f16x2 hA23 = gelu2(cA[2][r], cA[3][r]);
            f16x2 hB01 = gelu2(cB[0][r], cB[1][r]);
            f16x2 hB23 = gelu2(cB[2][r], cB[3][r]);
            *(f16x4*)&TA[(q * 4 + r) * WS + nl * 4] = (f16x4){hA01.x, hA01.y, hA23.x, hA23.y};
            *(f16x4*)&TB[(q * 4 + r) * WS + nl * 4] = (f16x4){hB01.x, hB01.y, hB23.x, hB23.y};
        }

        // ---- issue next pair's gathers (overlap layers 2-3) ----
        uint4 fyA2 = ((const uint4*)(xhf + ((size_t)((tA2 >> 15) * NN + nA2)) * OUT_DIM))[part];
        uint4 fyB2 = ((const uint4*)(xhf + ((size_t)((tB2 >> 15) * NN + nB2)) * OUT_DIM))[part];
        float2 ipA2, opA2, ipB2, opB2;
        if (part == 0) {
            ipA2 = ((const float2*)igrid)[nA2]; opA2 = ((const float2*)ogrid)[tA2 & (NN - 1)];
            ipB2 = ((const float2*)igrid)[nB2]; opB2 = ((const float2*)ogrid)[tB2 & (NN - 1)];
        }
        f16 xA0n = xhf[(size_t)tA2 * OUT_DIM + nl],  xA1n = xhf[(size_t)tA2 * OUT_DIM + 16 + nl];
        f16 xB0n = xhf[(size_t)tB2 * OUT_DIM + nl],  xB1n = xhf[(size_t)tB2 * OUT_DIM + 16 + nl];

        // ---- layer 2 ----
        aA0 = *(const f16x8*)&TA[nl * WS + q * 8];
        aA1 = *(const f16x8*)&TA[nl * WS + 32 + q * 8];
        aB0 = *(const f16x8*)&TB[nl * WS + q * 8];
        aB1 = *(const f16x8*)&TB[nl * WS + 32 + q * 8];
        #pragma unroll
        for (int nb = 0; nb < 4; nb++) {
            cA[nb] = (f32x4){b2v[nb], b2v[nb], b2v[nb], b2v[nb]};
            cB[nb] = (f32x4){b2v[nb], b2v[nb], b2v[nb], b2v[nb]};
        }
        #pragma unroll
        for (int nb = 0; nb < 4; nb++) {
            cA[nb] = __builtin_amdgcn_mfma_f32_16x16x32_f16(aA0, w2f[nb][0], cA[nb], 0, 0, 0);
            cB[nb] = __builtin_amdgcn_mfma_f32_16x16x32_f16(aB0, w2f[nb][0], cB[nb], 0, 0, 0);
            cA[nb] = __builtin_amdgcn_mfma_f32_16x16x32_f16(aA1, w2f[nb][1], cA[nb], 0, 0, 0);
            cB[nb] = __builtin_amdgcn_mfma_f32_16x16x32_f16(aB1, w2f[nb][1], cB[nb], 0, 0, 0);
        }
        #pragma unroll
        for (int r = 0; r < 4; r++) {
            f16x2 hA01 = gelu2(cA[0][r], cA[1][r]);
            f16x2 hA23 = gelu2(cA[2][r], cA[3][r]);
            f16x2 hB01 = gelu2(cB[0][r], cB[1][r]);
            f16x2 hB23 = gelu2(cB[2][r], cB[3][r]);
            *(f16x4*)&TA[(q * 4 + r) * WS + nl * 4] = (f16x4){hA01.x, hA01.y, hA23.x, hA23.y};
            *(f16x4*)&TB[(q * 4 + r) * WS + nl * 4] = (f16x4){hB01.x, hB01.y, hB23.x, hB23.y};
        }

        // ---- layer 3 ----
        aA0 = *(const f16x8*)&TA[nl * WS + q * 8];
        aA1 = *(const f16x8*)&TA[nl * WS + 32 + q * 8];
        aB0 = *(const f16x8*)&TB[nl * WS + q * 8];
        aB1 = *(const f16x8*)&TB[nl * WS + 32 + q * 8];
        f32x4 dA[2], dB[2];
        #pragma unroll
        for (int nb = 0; nb < 2; nb++) {
            dA[nb] = (f32x4){0.f, 0.f, 0.f, 0.f};
            dB[nb] = (f32x4){0.f, 0.f, 0.f, 0.f};
            dA[nb] = __builtin_amdgcn_mfma_f32_16x16x32_f16(aA0, w3f[nb][0], dA[nb], 0, 0, 0);
            dB[nb] = __builtin_amdgcn_mfma_f32_16x16x32_f16(aB0, w3f[nb][0], dB[nb], 0, 0, 0);
            dA[nb] = __builtin_amdgcn_mfma_f32_16x16x32_f16(aA1, w3f[nb][1], dA[nb], 0, 0, 0);
            dB[nb] = __builtin_amdgcn_mfma_f32_16x16x32_f16(aB1, w3f[nb][1], dB[nb], 0, 0, 0);
        }

        // ---- epilogues: mean over 16 edges + bias + residual, LN over 32 (DPP row sums) ----
        {
            float s0 = dA[0][0] + dA[0][1] + dA[0][2] + dA[0][3];
            float s1 = dA[1][0] + dA[1][1] + dA[1][2] + dA[1][3];
            float u0 = dB[0][0] + dB[0][1] + dB[0][2] + dB[0][3];
            float u1 = dB[1][0] + dB[1][1] + dB[1][2] + dB[1][3];
            s0 += __shfl_xor(s0, 16, 64); s0 += __shfl_xor(s0, 32, 64);
            s1 += __shfl_xor(s1, 16, 64); s1 += __shfl_xor(s1, 32, 64);
            u0 += __shfl_xor(u0, 16, 64); u0 += __shfl_xor(u0, 32, 64);
            u1 += __shfl_xor(u1, 16, 64); u1 += __shfl_xor(u1, 32, 64);

            float oA0 = s0 * 0.0625f + b3v[0] + rA0;
            float oA1 = s1 * 0.0625f + b3v[1] + rA1;
            float oB0 = u0 * 0.0625f + b3v[0] + rB0;
            float oB1 = u1 * 0.0625f + b3v[1] + rB1;

            float mA = rowsum16(oA0 + oA1) * (1.0f / 32.0f);
            float mB = rowsum16(oB0 + oB1) * (1.0f / 32.0f);
            float dA0 = oA0 - mA, dA1 = oA1 - mA, dB0 = oB0 - mB, dB1 = oB1 - mB;
            float vA = rowsum16(dA0 * dA0 + dA1 * dA1) * (1.0f / 32.0f);
            float vB = rowsum16(dB0 * dB0 + dB1 * dB1) * (1.0f / 32.0f);
            float rsA = rsqrtf(vA + 1e-5f);
            float rsB = rsqrtf(vB + 1e-5f);

            if (q == 0) {
                float* oa = out + (size_t)tA * OUT_DIM;
                float* ob = out + (size_t)tB * OUT_DIM;
                oa[nl]      = fmaf(dA0 * rsA, g0, be0);
                oa[16 + nl] = fmaf(dA1 * rsA, g1, be1);
                ob[nl]      = fmaf(dB0 * rsB, g0, be0);
                ob[16 + nl] = fmaf(dB1 * rsB, g1, be1);
            }
        }

        // ---- rotate prefetch state ----
        tA = tA2; tB = tB2;
        fyA = fyA2; fyB = fyB2;
        ipA = ipA2; opA = opA2; ipB = ipB2; opB = opB2;
        xA0 = xA0n; xA1 = xA1n; xB0 = xB0n; xB1 = xB1n;
    }
}

extern "C" void kernel_launch(void* const* d_in, const int* in_sizes, int n_in,
                              void* d_out, int out_size, void* d_ws, size_t ws_size,
                              hipStream_t stream) {
    const float* inp   = (const float*)d_in[0];
    const float* igrid = (const float*)d_in[1];
    const float* ogrid = (const float*)d_in[2];
    const int*   nbi   = (const int*)d_in[3];
    const float* Wp1   = (const float*)d_in[4];
    const float* bp1   = (const float*)d_in[5];
    const float* Wp2   = (const float*)d_in[6];
    const float* bp2   = (const float*)d_in[7];
    const float* Wk1   = (const float*)d_in[8];
    const float* bk1   = (const float*)d_in[9];
    const float* Wk2   = (const float*)d_in[10];
    const float* bk2   = (const float*)d_in[11];
    const float* Wk3   = (const float*)d_in[12];
    const float* bk3   = (const float*)d_in[13];
    const float* gma   = (const float*)d_in[14];
    const float* bta   = (const float*)d_in[15];
    float* out = (float*)d_out;
    f16* xhf = (f16*)d_ws;   // B*N*32 f16 = 8 MB

    point_mlp_kernel<<<1024, 256, 0, stream>>>(inp, Wp1, bp1, Wp2, bp2, xhf);
    gnn_edge_kernel<<<1024, 256, 0, stream>>>(xhf, igrid, ogrid, nbi,
                                              Wk1, bk1, Wk2, bk2, Wk3, bk3,
                                              gma, bta, out);
}